// Round 14
// baseline (284.858 us; speedup 1.0000x reference)
//
#include <hip/hip_runtime.h>
#include <cstdint>
#include <cstddef>

typedef __bf16 bf16x8 __attribute__((ext_vector_type(8)));
typedef float  f32x4  __attribute__((ext_vector_type(4)));
typedef int    i32x4  __attribute__((ext_vector_type(4)));

#define QMAX 7.0f
#define SCALE_MIN 2e-16f

#define BAR()     asm volatile("s_barrier" ::: "memory")
#define WAITVM(N) asm volatile("s_waitcnt vmcnt(" #N ")" ::: "memory")

// ---------------------------------------------------------------------------
// Kernel 1 (fused): blocks 0..255 quantize w -> wq[tap][o][c] (bf16);
// blocks 256..1167 zero the 1-cell halo of xpad.
// ---------------------------------------------------------------------------
__global__ __launch_bounds__(256) void pre_kernel(const float* __restrict__ w,
                                                  __bf16* __restrict__ wq,
                                                  __bf16* __restrict__ xpad) {
    const int t = threadIdx.x;
    if (blockIdx.x < 256) {
        const int o = blockIdx.x;
        const float* wo = w + (size_t)o * 2304;
        float vals[9];
        float m = 0.f;
        #pragma unroll
        for (int i = 0; i < 9; ++i) {
            float v = wo[t + i * 256];
            vals[i] = v;
            m = fmaxf(m, fabsf(v));
        }
        #pragma unroll
        for (int off = 32; off >= 1; off >>= 1) m = fmaxf(m, __shfl_down(m, off));
        __shared__ float red[4];
        __shared__ float s_scale;
        if ((t & 63) == 0) red[t >> 6] = m;
        __syncthreads();
        if (t == 0) {
            float am = fmaxf(fmaxf(red[0], red[1]), fmaxf(red[2], red[3]));
            s_scale = fmaxf(am / QMAX, SCALE_MIN);
        }
        __syncthreads();
        const float scale = s_scale;
        #pragma unroll
        for (int i = 0; i < 9; ++i) {
            int idx = t + i * 256;           // = c*9 + tap
            int c = idx / 9;
            int tap = idx - c * 9;
            float q = rintf(vals[i] / scale);      // round-half-even == jnp.round
            q = fminf(QMAX, fmaxf(-QMAX, q));
            wq[(size_t)tap * 65536 + (size_t)o * 256 + c] = (__bf16)(q * scale);
        }
    } else {
        const int g = (blockIdx.x - 256) * 256 + t;
        const int cvec = g & 31;
        const int r    = g >> 5;
        const int n    = r / 228;
        const int pos  = r - n * 228;
        if (n >= 32) return;
        int h, wcol;
        if      (pos < 58)  { h = 0;          wcol = pos; }
        else if (pos < 116) { h = 57;         wcol = pos - 58; }
        else if (pos < 172) { h = pos - 115;  wcol = 0; }
        else                { h = pos - 171;  wcol = 57; }
        i32x4* dst = (i32x4*)(xpad + (((size_t)n * 58 + h) * 58 + wcol) * 256);
        dst[cvec] = (i32x4){0, 0, 0, 0};
    }
}

// ---------------------------------------------------------------------------
// Kernel 2: x NCHW fp32 [32,256,56,56] -> padded NHWC bf16 [32][58][58][256]
// ---------------------------------------------------------------------------
__global__ __launch_bounds__(256) void convert_x_kernel(const float* __restrict__ x,
                                                        __bf16* __restrict__ xpad) {
    __shared__ float tile[32][33];
    const int n  = blockIdx.z;
    const int c0 = blockIdx.y * 32;
    const int p0 = blockIdx.x * 32;
    const int tx = threadIdx.x & 31;
    const int ty = threadIdx.x >> 5;

    #pragma unroll
    for (int r = 0; r < 4; ++r) {
        int c = c0 + ty + r * 8;
        tile[ty + r * 8][tx] = x[((size_t)(n * 256 + c)) * 3136 + p0 + tx];
    }
    __syncthreads();
    #pragma unroll
    for (int r = 0; r < 4; ++r) {
        int p = p0 + ty + r * 8;
        int h = p / 56, wcol = p - h * 56;
        xpad[(((size_t)n * 58 + h + 1) * 58 + (wcol + 1)) * 256 + c0 + tx] =
            (__bf16)tile[tx][ty + r * 8];
    }
}

// ---------------------------------------------------------------------------
// Kernel 3: implicit-GEMM conv — R13 instruction stream at 3 blocks/CU.
// Block 256o x 128pos, 256 thr (4 waves 2Mx2N), per-wave 128x64 as 8x4 frags
// of mfma_f32_16x16x32_bf16; 12 ds_read_b128 / 32 MFMA per BK=32 step;
// 72 K-steps. DOUBLE-buffered LDS (2 x 24 KB = 48 KB) -> 3 blocks/CU
// (12 waves): co-resident blocks fill each other's stage/vmcnt/barrier
// stalls (m114) — the one axis not yet isolated on this chassis.
// Schedule per step (stage moved AFTER the barrier — required for dbuf):
//   WAITVM(0) [only outstanding = this step's 6 loads, issued one full step
//   ago] -> BAR [proves all waves consumed buf[s-1]: each wave's MFMAs
//   drained its reads via lgkmcnt before reaching this BAR] ->
//   STAGE(s+1 -> other buf) -> 12 ds_read + 32 MFMA.
// Swizzle (R12/R13, measured 0 conflicts): stored 16B-slot = chunk ^
// ((row>>1)&3) on 64B rows; source pre-swizzled (tid&3)^((tid>>3)&3);
// gload_lds dest linear. Grid 784 = 8*98 XCD-bijective.
// ---------------------------------------------------------------------------
__device__ __forceinline__ void gload_lds16(const void* g, void* l) {
    __builtin_amdgcn_global_load_lds((const __attribute__((address_space(1))) void*)g,
                                     (__attribute__((address_space(3))) void*)l,
                                     16, 0, 0);
}

__global__ __launch_bounds__(256, 3) void conv_mfma_kernel(const __bf16* __restrict__ xpad,
                                                           const __bf16* __restrict__ wq,
                                                           float* __restrict__ out) {
    extern __shared__ __align__(16) char lds[];   // 49152 B = 2 x 24576
    const int tid  = threadIdx.x;
    const int wv   = tid >> 6;          // 0..3
    const int lane = tid & 63;
    const int l15  = lane & 15;
    const int bid  = blockIdx.x;
    const int swz  = (bid & 7) * 98 + (bid >> 3);    // 784 = 8*98 bijection
    const int p0   = swz * 128;

    const int wm = wv >> 1;        // 0..1 : o 128-half
    const int wn = wv & 1;         // 0..1 : pos 64-half

    // ---- staging setup: 6 issues/step of 4 KB (64 rows x 64 B) -----------
    const int trow   = tid >> 2;                     // 0..63 row within issue
    const int schunk = (tid & 3) ^ ((tid >> 3) & 3); // pre-swizzled src slot
    const __bf16* pA[4];
    #pragma unroll
    for (int j = 0; j < 4; ++j)
        pA[j] = wq + (size_t)(j * 64 + trow) * 256 + schunk * 8;
    const __bf16* pBs[2];
    #pragma unroll
    for (int j = 0; j < 2; ++j) {
        int pos = p0 + j * 64 + trow;                // < 100352 (exact tiling)
        int ni = pos / 3136;
        int hw = pos - ni * 3136;
        int h = hw / 56, w = hw - h * 56;
        pBs[j] = xpad + (((size_t)ni * 58 + h) * 58 + w) * 256 + schunk * 8;
    }
    // wave-uniform LDS dest bases (HW adds lane*16):
    const int adst = wv * 1024;            // + j*4096   (A region: 16 KB)
    const int bdst = 16384 + wv * 1024;    // + j*4096   (B region: 8 KB)

    // ---- fragment read offsets -------------------------------------------
    const int aoff0 = l15 * 64 + ((((lane >> 4) ^ ((l15 >> 1) & 3))) << 4);
    const int abase = wm * 8192;                      // A rows wm*128.. (+m*1024)
    const int bbase = 16384 + wn * 4096;              // B rows wn*64..  (+n*1024)

    f32x4 acc[8][4];
    #pragma unroll
    for (int m = 0; m < 8; ++m)
        #pragma unroll
        for (int n = 0; n < 4; ++n)
            acc[m][n] = (f32x4){0.f, 0.f, 0.f, 0.f};

    // ---- stage helper: 6 gloads (A0..A3, B0, B1) = 6 vmcnt entries -------
    #define STAGE(STEP, BUF)                                                  \
        {                                                                     \
            const int tap_ = (STEP) >> 3, cc_ = (STEP) & 7;                   \
            const int kh_ = tap_ / 3, kw_ = tap_ - kh_ * 3;                   \
            const size_t aoff_ = (size_t)tap_ * 65536 + cc_ * 32;             \
            const size_t boff_ = (size_t)(kh_ * 58 + kw_) * 256 + cc_ * 32;   \
            gload_lds16(pA[0] + aoff_, (BUF) + adst);                         \
            gload_lds16(pA[1] + aoff_, (BUF) + adst + 4096);                  \
            gload_lds16(pA[2] + aoff_, (BUF) + adst + 8192);                  \
            gload_lds16(pA[3] + aoff_, (BUF) + adst + 12288);                 \
            gload_lds16(pBs[0] + boff_, (BUF) + bdst);                        \
            gload_lds16(pBs[1] + boff_, (BUF) + bdst + 4096);                 \
        }

    STAGE(0, lds);                         // prologue: step 0 -> buf0

    int cur = 0;                           // byte offset of read buffer
    #pragma unroll 1
    for (int s = 0; s < 72; ++s) {
        WAITVM(0);                         // this step's 6 loads (1 step in flight)
        BAR();                             // all waves done reading buf[s-1]
        const int nxt = cur ^ 24576;
        if (s < 71) STAGE(s + 1, lds + nxt);
        const char* B = lds + cur;

        bf16x8 a[4], b[4];
        // ---- phase 0: m0..3 x n0..3 ----
        #pragma unroll
        for (int m = 0; m < 4; ++m)
            a[m] = *(const bf16x8*)(B + abase + m * 1024 + aoff0);
        #pragma unroll
        for (int n = 0; n < 4; ++n)
            b[n] = *(const bf16x8*)(B + bbase + n * 1024 + aoff0);
        __builtin_amdgcn_s_setprio(1);
        #pragma unroll
        for (int m = 0; m < 4; ++m)
            #pragma unroll
            for (int n = 0; n < 4; ++n)
                acc[m][n] = __builtin_amdgcn_mfma_f32_16x16x32_bf16(a[m], b[n], acc[m][n], 0, 0, 0);
        __builtin_amdgcn_s_setprio(0);
        // ---- phase 1: m4..7 x n0..3 ----
        #pragma unroll
        for (int m = 0; m < 4; ++m)
            a[m] = *(const bf16x8*)(B + abase + (m + 4) * 1024 + aoff0);
        __builtin_amdgcn_s_setprio(1);
        #pragma unroll
        for (int m = 0; m < 4; ++m)
            #pragma unroll
            for (int n = 0; n < 4; ++n)
                acc[m + 4][n] = __builtin_amdgcn_mfma_f32_16x16x32_bf16(a[m], b[n], acc[m + 4][n], 0, 0, 0);
        __builtin_amdgcn_s_setprio(0);
        cur = nxt;
    }
    #undef STAGE

    // ---- epilogue: 16x16 C/D: col=lane&15, row=(lane>>4)*4 + r -----------
    #pragma unroll
    for (int n = 0; n < 4; ++n) {
        const int pos = p0 + wn * 64 + n * 16 + l15;
        const int ni = pos / 3136;
        const int hw = pos - ni * 3136;
        float* ob = out + (size_t)ni * 802816 + hw;
        #pragma unroll
        for (int m = 0; m < 8; ++m) {
            const int om = wm * 128 + m * 16 + (lane >> 4) * 4;
            #pragma unroll
            for (int r = 0; r < 4; ++r)
                ob[(size_t)(om + r) * 3136] = acc[m][n][r];
        }
    }
}

// ---------------------------------------------------------------------------
// Fallback: naive direct conv (only if ws_size too small).
// ---------------------------------------------------------------------------
__global__ __launch_bounds__(256) void conv_naive_kernel(const float* __restrict__ x,
                                                         const float* __restrict__ w,
                                                         float* __restrict__ out) {
    const int n = blockIdx.z;
    const int o = blockIdx.y;
    const int strip = blockIdx.x;
    __shared__ float wqs[2304];
    __shared__ float red[4];
    __shared__ float s_scale;
    const float* wo = w + (size_t)o * 2304;
    float m = 0.f;
    for (int i = threadIdx.x; i < 2304; i += 256) m = fmaxf(m, fabsf(wo[i]));
    #pragma unroll
    for (int off = 32; off >= 1; off >>= 1) m = fmaxf(m, __shfl_down(m, off));
    if ((threadIdx.x & 63) == 0) red[threadIdx.x >> 6] = m;
    __syncthreads();
    if (threadIdx.x == 0) {
        float am = fmaxf(fmaxf(red[0], red[1]), fmaxf(red[2], red[3]));
        s_scale = fmaxf(am / QMAX, SCALE_MIN);
    }
    __syncthreads();
    const float scale = s_scale;
    for (int i = threadIdx.x; i < 2304; i += 256) {
        float q = rintf(wo[i] / scale);
        q = fminf(QMAX, fmaxf(-QMAX, q));
        wqs[i] = q * scale;
    }
    __syncthreads();
    int p = strip * 256 + threadIdx.x;
    if (p >= 3136) return;
    int h = p / 56, wcol = p - h * 56;
    float acc = 0.f;
    for (int c = 0; c < 256; ++c) {
        const float* xc = x + ((size_t)(n * 256 + c)) * 3136;
        const float* wk = wqs + c * 9;
        #pragma unroll
        for (int kh = 0; kh < 3; ++kh) {
            int hh = h + kh - 1;
            if (hh < 0 || hh > 55) continue;
            #pragma unroll
            for (int kw = 0; kw < 3; ++kw) {
                int ww2 = wcol + kw - 1;
                if (ww2 < 0 || ww2 > 55) continue;
                acc += xc[hh * 56 + ww2] * wk[kh * 3 + kw];
            }
        }
    }
    out[((size_t)(n * 256 + o)) * 3136 + p] = acc;
}

// ---------------------------------------------------------------------------
extern "C" void kernel_launch(void* const* d_in, const int* in_sizes, int n_in,
                              void* d_out, int out_size, void* d_ws, size_t ws_size,
                              hipStream_t stream) {
    const float* x = (const float*)d_in[0];
    const float* w = (const float*)d_in[1];
    float* out = (float*)d_out;

    const size_t WQ_BYTES   = 9ull * 256 * 256 * 2;            // 1,179,648
    const size_t XPAD_OFF   = WQ_BYTES;
    const size_t XPAD_BYTES = 32ull * 58 * 58 * 256 * 2;       // 55,083,008

    if (ws_size >= XPAD_OFF + XPAD_BYTES) {
        __bf16* wq   = (__bf16*)d_ws;
        __bf16* xpad = (__bf16*)((char*)d_ws + XPAD_OFF);
        hipFuncSetAttribute((const void*)conv_mfma_kernel,
                            hipFuncAttributeMaxDynamicSharedMemorySize, 49152);
        pre_kernel<<<1168, 256, 0, stream>>>(w, wq, xpad);     // quant + halo zero
        convert_x_kernel<<<dim3(98, 8, 32), 256, 0, stream>>>(x, xpad);
        conv_mfma_kernel<<<784, 256, 49152, stream>>>(xpad, wq, out);
    } else {
        conv_naive_kernel<<<dim3(13, 256, 32), 256, 0, stream>>>(x, w, out);
    }
}

// Round 15
// 164.677 us; speedup vs baseline: 1.7298x; 1.7298x over previous
//
#include <hip/hip_runtime.h>
#include <cstdint>
#include <cstddef>

typedef __bf16 bf16x8 __attribute__((ext_vector_type(8)));
typedef float  f32x4  __attribute__((ext_vector_type(4)));
typedef int    i32x4  __attribute__((ext_vector_type(4)));

#define QMAX 7.0f
#define SCALE_MIN 2e-16f

#define BAR()     asm volatile("s_barrier" ::: "memory")
#define WAITVM(N) asm volatile("s_waitcnt vmcnt(" #N ")" ::: "memory")

// ---------------------------------------------------------------------------
// Kernel 1 (fused): blocks 0..255 quantize w -> wq[tap][o][c] (bf16);
// blocks 256..1167 zero the 1-cell halo of xpad. Saves one dispatch.
// ---------------------------------------------------------------------------
__global__ __launch_bounds__(256) void pre_kernel(const float* __restrict__ w,
                                                  __bf16* __restrict__ wq,
                                                  __bf16* __restrict__ xpad) {
    const int t = threadIdx.x;
    if (blockIdx.x < 256) {
        // ---- per-output-channel fake-quant ----
        const int o = blockIdx.x;
        const float* wo = w + (size_t)o * 2304;
        float vals[9];
        float m = 0.f;
        #pragma unroll
        for (int i = 0; i < 9; ++i) {
            float v = wo[t + i * 256];
            vals[i] = v;
            m = fmaxf(m, fabsf(v));
        }
        #pragma unroll
        for (int off = 32; off >= 1; off >>= 1) m = fmaxf(m, __shfl_down(m, off));
        __shared__ float red[4];
        __shared__ float s_scale;
        if ((t & 63) == 0) red[t >> 6] = m;
        __syncthreads();
        if (t == 0) {
            float am = fmaxf(fmaxf(red[0], red[1]), fmaxf(red[2], red[3]));
            s_scale = fmaxf(am / QMAX, SCALE_MIN);
        }
        __syncthreads();
        const float scale = s_scale;
        #pragma unroll
        for (int i = 0; i < 9; ++i) {
            int idx = t + i * 256;           // = c*9 + tap
            int c = idx / 9;
            int tap = idx - c * 9;
            float q = rintf(vals[i] / scale);      // round-half-even == jnp.round
            q = fminf(QMAX, fmaxf(-QMAX, q));
            wq[(size_t)tap * 65536 + (size_t)o * 256 + c] = (__bf16)(q * scale);
        }
    } else {
        // ---- halo zero: 32 images x 228 border cells x 256 bf16 ----
        const int g = (blockIdx.x - 256) * 256 + t;
        const int cvec = g & 31;
        const int r    = g >> 5;
        const int n    = r / 228;
        const int pos  = r - n * 228;
        if (n >= 32) return;
        int h, wcol;
        if      (pos < 58)  { h = 0;          wcol = pos; }
        else if (pos < 116) { h = 57;         wcol = pos - 58; }
        else if (pos < 172) { h = pos - 115;  wcol = 0; }
        else                { h = pos - 171;  wcol = 57; }
        i32x4* dst = (i32x4*)(xpad + (((size_t)n * 58 + h) * 58 + wcol) * 256);
        dst[cvec] = (i32x4){0, 0, 0, 0};
    }
}

// ---------------------------------------------------------------------------
// Kernel 2: x NCHW fp32 [32,256,56,56] -> padded NHWC bf16 [32][58][58][256]
// ---------------------------------------------------------------------------
__global__ __launch_bounds__(256) void convert_x_kernel(const float* __restrict__ x,
                                                        __bf16* __restrict__ xpad) {
    __shared__ float tile[32][33];
    const int n  = blockIdx.z;
    const int c0 = blockIdx.y * 32;
    const int p0 = blockIdx.x * 32;
    const int tx = threadIdx.x & 31;
    const int ty = threadIdx.x >> 5;

    #pragma unroll
    for (int r = 0; r < 4; ++r) {
        int c = c0 + ty + r * 8;
        tile[ty + r * 8][tx] = x[((size_t)(n * 256 + c)) * 3136 + p0 + tx];
    }
    __syncthreads();
    #pragma unroll
    for (int r = 0; r < 4; ++r) {
        int p = p0 + ty + r * 8;
        int h = p / 56, wcol = p - h * 56;
        xpad[(((size_t)n * 58 + h + 1) * 58 + (wcol + 1)) * 256 + c0 + tx] =
            (__bf16)tile[tx][ty + r * 8];
    }
}

// ---------------------------------------------------------------------------
// Kernel 3: implicit-GEMM conv — the session's best-measured configuration
// (R13 = R12 conv stream + static grid; R14's occupancy/dbuf experiment
// regressed 143->264us and is reverted).
// Block 256o x 128pos, 256 thr (4 waves 2Mx2N), per-wave 128x64 as 8x4 frags
// of mfma_f32_16x16x32_bf16; 12 ds_read_b128 / 32 MFMA per BK=32 step;
// 72 K-steps. TRIPLE-buffered LDS (3 x 24 KB = 72 KB) -> 2 blocks/CU.
// Per step: STAGE(s+1) 6 gloads at top -> WAITVM(6) counted -> ONE BAR ->
// 12 ds_read + 32 MFMA (compiler partial-lgkmcnt scheduling).
// Swizzle (R12, measured 0 conflicts): stored 16B-slot = chunk ^ ((row>>1)&3)
// on 64B rows; staging source pre-swizzled (tid&3)^((tid>>3)&3); gload_lds
// dest linear (both-sides rule).
// Grid: static 784 = 8*98 XCD-bijective (ticket/persistent = null in conv,
// -9us wall, R12; drain-vmcnt dbuf = -121us, R14).
// ---------------------------------------------------------------------------
__device__ __forceinline__ void gload_lds16(const void* g, void* l) {
    __builtin_amdgcn_global_load_lds((const __attribute__((address_space(1))) void*)g,
                                     (__attribute__((address_space(3))) void*)l,
                                     16, 0, 0);
}

__global__ __launch_bounds__(256, 2) void conv_mfma_kernel(const __bf16* __restrict__ xpad,
                                                           const __bf16* __restrict__ wq,
                                                           float* __restrict__ out) {
    extern __shared__ __align__(16) char lds[];   // 73728 B = 3 x 24576
    const int tid  = threadIdx.x;
    const int wv   = tid >> 6;          // 0..3
    const int lane = tid & 63;
    const int l15  = lane & 15;
    const int bid  = blockIdx.x;
    const int swz  = (bid & 7) * 98 + (bid >> 3);    // 784 = 8*98 bijection
    const int p0   = swz * 128;

    const int wm = wv >> 1;        // 0..1 : o 128-half
    const int wn = wv & 1;         // 0..1 : pos 64-half

    // ---- staging setup: 6 issues/step of 4 KB (64 rows x 64 B) -----------
    const int trow   = tid >> 2;                     // 0..63 row within issue
    const int schunk = (tid & 3) ^ ((tid >> 3) & 3); // pre-swizzled src slot
    const __bf16* pA[4];
    #pragma unroll
    for (int j = 0; j < 4; ++j)
        pA[j] = wq + (size_t)(j * 64 + trow) * 256 + schunk * 8;
    const __bf16* pBs[2];
    #pragma unroll
    for (int j = 0; j < 2; ++j) {
        int pos = p0 + j * 64 + trow;                // < 100352 (exact tiling)
        int ni = pos / 3136;
        int hw = pos - ni * 3136;
        int h = hw / 56, w = hw - h * 56;
        pBs[j] = xpad + (((size_t)ni * 58 + h) * 58 + w) * 256 + schunk * 8;
    }
    // wave-uniform LDS dest bases (HW adds lane*16):
    const int adst = wv * 1024;            // + j*4096   (A region: 16 KB)
    const int bdst = 16384 + wv * 1024;    // + j*4096   (B region: 8 KB)

    // ---- fragment read offsets -------------------------------------------
    // frag row = <mult of 16> + l15; stored slot = (lane>>4) ^ ((l15>>1)&3).
    const int aoff0 = l15 * 64 + ((((lane >> 4) ^ ((l15 >> 1) & 3))) << 4);
    const int abase = wm * 8192;                      // A rows wm*128.. (+m*1024)
    const int bbase = 16384 + wn * 4096;              // B rows wn*64..  (+n*1024)

    f32x4 acc[8][4];
    #pragma unroll
    for (int m = 0; m < 8; ++m)
        #pragma unroll
        for (int n = 0; n < 4; ++n)
            acc[m][n] = (f32x4){0.f, 0.f, 0.f, 0.f};

    // ---- stage helper: 6 gloads (A0..A3, B0, B1) = 6 vmcnt entries -------
    #define STAGE(STEP, BUF)                                                  \
        {                                                                     \
            const int tap_ = (STEP) >> 3, cc_ = (STEP) & 7;                   \
            const int kh_ = tap_ / 3, kw_ = tap_ - kh_ * 3;                   \
            const size_t aoff_ = (size_t)tap_ * 65536 + cc_ * 32;             \
            const size_t boff_ = (size_t)(kh_ * 58 + kw_) * 256 + cc_ * 32;   \
            gload_lds16(pA[0] + aoff_, (BUF) + adst);                         \
            gload_lds16(pA[1] + aoff_, (BUF) + adst + 4096);                  \
            gload_lds16(pA[2] + aoff_, (BUF) + adst + 8192);                  \
            gload_lds16(pA[3] + aoff_, (BUF) + adst + 12288);                 \
            gload_lds16(pBs[0] + boff_, (BUF) + bdst);                        \
            gload_lds16(pBs[1] + boff_, (BUF) + bdst + 4096);                 \
        }

    STAGE(0, lds);                         // prologue: step 0 -> buf0

    int co = 0;                            // (s%3)*24576
    #pragma unroll 1
    for (int s = 0; s < 72; ++s) {
        int no = co + 24576; if (no == 73728) no = 0;
        if (s < 71) {
            STAGE(s + 1, lds + no);
            WAITVM(6);
        } else {
            WAITVM(0);
        }
        BAR();
        const char* B = lds + co;

        bf16x8 a[4], b[4];
        // ---- phase 0: m0..3 x n0..3 ----
        #pragma unroll
        for (int m = 0; m < 4; ++m)
            a[m] = *(const bf16x8*)(B + abase + m * 1024 + aoff0);
        #pragma unroll
        for (int n = 0; n < 4; ++n)
            b[n] = *(const bf16x8*)(B + bbase + n * 1024 + aoff0);
        __builtin_amdgcn_s_setprio(1);
        #pragma unroll
        for (int m = 0; m < 4; ++m)
            #pragma unroll
            for (int n = 0; n < 4; ++n)
                acc[m][n] = __builtin_amdgcn_mfma_f32_16x16x32_bf16(a[m], b[n], acc[m][n], 0, 0, 0);
        __builtin_amdgcn_s_setprio(0);
        // ---- phase 1: m4..7 x n0..3 ----
        #pragma unroll
        for (int m = 0; m < 4; ++m)
            a[m] = *(const bf16x8*)(B + abase + (m + 4) * 1024 + aoff0);
        __builtin_amdgcn_s_setprio(1);
        #pragma unroll
        for (int m = 0; m < 4; ++m)
            #pragma unroll
            for (int n = 0; n < 4; ++n)
                acc[m + 4][n] = __builtin_amdgcn_mfma_f32_16x16x32_bf16(a[m], b[n], acc[m + 4][n], 0, 0, 0);
        __builtin_amdgcn_s_setprio(0);
        co = no;
    }
    #undef STAGE

    // ---- epilogue: 16x16 C/D: col=lane&15, row=(lane>>4)*4 + r -----------
    #pragma unroll
    for (int n = 0; n < 4; ++n) {
        const int pos = p0 + wn * 64 + n * 16 + l15;
        const int ni = pos / 3136;
        const int hw = pos - ni * 3136;
        float* ob = out + (size_t)ni * 802816 + hw;
        #pragma unroll
        for (int m = 0; m < 8; ++m) {
            const int om = wm * 128 + m * 16 + (lane >> 4) * 4;
            #pragma unroll
            for (int r = 0; r < 4; ++r)
                ob[(size_t)(om + r) * 3136] = acc[m][n][r];
        }
    }
}

// ---------------------------------------------------------------------------
// Fallback: naive direct conv (only if ws_size too small).
// ---------------------------------------------------------------------------
__global__ __launch_bounds__(256) void conv_naive_kernel(const float* __restrict__ x,
                                                         const float* __restrict__ w,
                                                         float* __restrict__ out) {
    const int n = blockIdx.z;
    const int o = blockIdx.y;
    const int strip = blockIdx.x;
    __shared__ float wqs[2304];
    __shared__ float red[4];
    __shared__ float s_scale;
    const float* wo = w + (size_t)o * 2304;
    float m = 0.f;
    for (int i = threadIdx.x; i < 2304; i += 256) m = fmaxf(m, fabsf(wo[i]));
    #pragma unroll
    for (int off = 32; off >= 1; off >>= 1) m = fmaxf(m, __shfl_down(m, off));
    if ((threadIdx.x & 63) == 0) red[threadIdx.x >> 6] = m;
    __syncthreads();
    if (threadIdx.x == 0) {
        float am = fmaxf(fmaxf(red[0], red[1]), fmaxf(red[2], red[3]));
        s_scale = fmaxf(am / QMAX, SCALE_MIN);
    }
    __syncthreads();
    const float scale = s_scale;
    for (int i = threadIdx.x; i < 2304; i += 256) {
        float q = rintf(wo[i] / scale);
        q = fminf(QMAX, fmaxf(-QMAX, q));
        wqs[i] = q * scale;
    }
    __syncthreads();
    int p = strip * 256 + threadIdx.x;
    if (p >= 3136) return;
    int h = p / 56, wcol = p - h * 56;
    float acc = 0.f;
    for (int c = 0; c < 256; ++c) {
        const float* xc = x + ((size_t)(n * 256 + c)) * 3136;
        const float* wk = wqs + c * 9;
        #pragma unroll
        for (int kh = 0; kh < 3; ++kh) {
            int hh = h + kh - 1;
            if (hh < 0 || hh > 55) continue;
            #pragma unroll
            for (int kw = 0; kw < 3; ++kw) {
                int ww2 = wcol + kw - 1;
                if (ww2 < 0 || ww2 > 55) continue;
                acc += xc[hh * 56 + ww2] * wk[kh * 3 + kw];
            }
        }
    }
    out[((size_t)(n * 256 + o)) * 3136 + p] = acc;
}

// ---------------------------------------------------------------------------
extern "C" void kernel_launch(void* const* d_in, const int* in_sizes, int n_in,
                              void* d_out, int out_size, void* d_ws, size_t ws_size,
                              hipStream_t stream) {
    const float* x = (const float*)d_in[0];
    const float* w = (const float*)d_in[1];
    float* out = (float*)d_out;

    const size_t WQ_BYTES   = 9ull * 256 * 256 * 2;            // 1,179,648
    const size_t XPAD_OFF   = WQ_BYTES;
    const size_t XPAD_BYTES = 32ull * 58 * 58 * 256 * 2;       // 55,083,008

    if (ws_size >= XPAD_OFF + XPAD_BYTES) {
        __bf16* wq   = (__bf16*)d_ws;
        __bf16* xpad = (__bf16*)((char*)d_ws + XPAD_OFF);
        hipFuncSetAttribute((const void*)conv_mfma_kernel,
                            hipFuncAttributeMaxDynamicSharedMemorySize, 73728);
        pre_kernel<<<1168, 256, 0, stream>>>(w, wq, xpad);     // quant + halo zero
        convert_x_kernel<<<dim3(98, 8, 32), 256, 0, stream>>>(x, xpad);
        conv_mfma_kernel<<<784, 256, 73728, stream>>>(xpad, wq, out);
    } else {
        conv_naive_kernel<<<dim3(13, 256, 32), 256, 0, stream>>>(x, w, out);
    }
}